// Round 5
// baseline (410.931 us; speedup 1.0000x reference)
//
#include <hip/hip_runtime.h>
#include <hip/hip_bf16.h>

#define BATCH 16
#define SEQ   512
#define HID   768
#define NH    12
#define HD    64
#define NS    5
#define LOG2E 1.44269504f

typedef __attribute__((ext_vector_type(8))) short short8;
typedef __attribute__((ext_vector_type(4))) float floatx4;

#define MFMA16(a, b, c) __builtin_amdgcn_mfma_f32_16x16x32_bf16((a), (b), (c), 0, 0, 0)

// async global->LDS, 16B per lane, dest = ldsbase + lane*16
#define GLOAD16(gp, lp) __builtin_amdgcn_global_load_lds( \
    (const __attribute__((address_space(1))) unsigned*)(gp), \
    (__attribute__((address_space(3))) unsigned*)(lp), 16, 0, 0)

static __device__ __forceinline__ short f2bs(float f) {
    // fp32 -> bf16 RNE (finite inputs)
    unsigned x = __builtin_bit_cast(unsigned, f);
    return (short)((x + 0x7fffu + ((x >> 16) & 1u)) >> 16);
}

// ---------- fused prep: hidden cvt | W cvt | bili transpose | mask pack ----------
// blocks [0,3072): hidden  [3072,3936): W (3x288)  [3936,3996): bilit  [3996,8092): pack_mask
__global__ __launch_bounds__(256) void prep_kernel(
    const float* __restrict__ hidden, const float* __restrict__ wq,
    const float* __restrict__ wk, const float* __restrict__ wv,
    const float* __restrict__ bili, const float* __restrict__ smask,
    short* __restrict__ xb, short* __restrict__ Wb, short* __restrict__ bltb,
    uchar4* __restrict__ mpk)
{
    __shared__ short Tl[64][72];
    const int bid = blockIdx.x, tid = threadIdx.x;

    if (bid < 3072) {                       // hidden: 786432 groups of 8
        int i = bid * 256 + tid;
        float4 a = ((const float4*)hidden)[2 * i];
        float4 b = ((const float4*)hidden)[2 * i + 1];
        short8 o;
        o[0] = f2bs(a.x); o[1] = f2bs(a.y); o[2] = f2bs(a.z); o[3] = f2bs(a.w);
        o[4] = f2bs(b.x); o[5] = f2bs(b.y); o[6] = f2bs(b.z); o[7] = f2bs(b.w);
        ((short8*)xb)[i] = o;
    } else if (bid < 3936) {                // W: 3 mats x 288 blocks
        int seg = bid - 3072;
        int mat = seg / 288, blk = seg % 288;
        const float* src = (mat == 0) ? wq : (mat == 1) ? wk : wv;
        int i = blk * 256 + tid;
        float4 a = ((const float4*)src)[2 * i];
        float4 b = ((const float4*)src)[2 * i + 1];
        short8 o;
        o[0] = f2bs(a.x); o[1] = f2bs(a.y); o[2] = f2bs(a.z); o[3] = f2bs(a.w);
        o[4] = f2bs(b.x); o[5] = f2bs(b.y); o[6] = f2bs(b.z); o[7] = f2bs(b.w);
        ((short8*)(Wb + (size_t)mat * HID * HID))[i] = o;
    } else if (bid < 3996) {                // bilit: [s,h,p,q] -> bf16 [s,h,q,p]
        int sh = bid - 3936;
        const float* src = bili + (size_t)sh * 4096;
        short* dst = bltb + (size_t)sh * 4096;
        for (int t = tid; t < 4096; t += 256) Tl[t >> 6][t & 63] = f2bs(src[t]);
        __syncthreads();
        for (int t = tid; t < 4096; t += 256) dst[t] = Tl[t & 63][t >> 6];
    } else {                                // pack 5 masks into bitfield bytes
        int i = (bid - 3996) * 256 + tid;   // over B*L*L/4
        const size_t BLL4 = (size_t)BATCH * SEQ * SEQ / 4;
        const float4* f = (const float4*)smask;
        unsigned b0 = 0, b1 = 0, b2 = 0, b3 = 0;
#pragma unroll
        for (int s = 0; s < NS; ++s) {
            float4 v = f[(size_t)s * BLL4 + i];
            b0 |= (v.x != 0.f) ? (1u << s) : 0u;
            b1 |= (v.y != 0.f) ? (1u << s) : 0u;
            b2 |= (v.z != 0.f) ? (1u << s) : 0u;
            b3 |= (v.w != 0.f) ? (1u << s) : 0u;
        }
        mpk[i] = make_uchar4((unsigned char)b0, (unsigned char)b1, (unsigned char)b2, (unsigned char)b3);
    }
}

// ---------- QKV projection, 128x128 tile + global_load_lds ----------
// q pre-scaled by 0.125*LOG2E (fold softmax scale + exp2 conversion); k raw; v -> [B,H,D,L].
__global__ __launch_bounds__(256) void proj_mfma(
    const short* __restrict__ xb, const short* __restrict__ Wb,
    const float* __restrict__ bq, const float* __restrict__ bk, const float* __restrict__ bv,
    short* __restrict__ qo, short* __restrict__ ko, short* __restrict__ vto)
{
    __shared__ short As[128 * 32];
    __shared__ short Bs[128 * 32];

    const int tid = threadIdx.x, lane = tid & 63, w = tid >> 6;
    const int q4 = lane >> 4, c15 = lane & 15;
    const int m0 = blockIdx.x * 128, n0 = blockIdx.y * 128;
    const int wrow = (w & 1) * 64, wcol = (w >> 1) * 64;

    const int srow = lane >> 2;
    const int scol = (lane & 3) * 8;
    const short* gA = xb + (size_t)(m0 + w * 32 + srow) * HID + scol;
    const short* gB = Wb + (size_t)(n0 + w * 32 + srow) * HID + scol;
    short* lA = As + w * 1024;
    short* lB = Bs + w * 1024;

    floatx4 acc[4][4];
#pragma unroll
    for (int i = 0; i < 4; ++i)
#pragma unroll
        for (int j = 0; j < 4; ++j) acc[i][j] = (floatx4){0.f, 0.f, 0.f, 0.f};

    for (int k0 = 0; k0 < HID; k0 += 32) {
        __syncthreads();
        GLOAD16(gA + k0,            lA);
        GLOAD16(gA + k0 + 16 * HID, lA + 512);
        GLOAD16(gB + k0,            lB);
        GLOAD16(gB + k0 + 16 * HID, lB + 512);
        __syncthreads();

        short8 af[4], bf[4];
#pragma unroll
        for (int ri = 0; ri < 4; ++ri)
            af[ri] = *(const short8*)&As[(wrow + ri * 16 + c15) * 32 + q4 * 8];
#pragma unroll
        for (int ci = 0; ci < 4; ++ci)
            bf[ci] = *(const short8*)&Bs[(wcol + ci * 16 + c15) * 32 + q4 * 8];
#pragma unroll
        for (int ri = 0; ri < 4; ++ri)
#pragma unroll
            for (int ci = 0; ci < 4; ++ci)
                acc[ri][ci] = MFMA16(af[ri], bf[ci], acc[ri][ci]);
    }

    const int matq = n0 / HID;
    const float* bias = (matq == 0) ? bq : (matq == 1) ? bk : bv;
    const float qscale = 0.125f * LOG2E;

#pragma unroll
    for (int ci = 0; ci < 4; ++ci) {
        const int nm = (n0 - matq * HID) + wcol + ci * 16 + c15;
        const int h = nm >> 6, d = nm & 63;
        const float bvv = bias[nm];
#pragma unroll
        for (int ri = 0; ri < 4; ++ri) {
            const int mg0 = m0 + wrow + ri * 16 + q4 * 4;
            const int bb = mg0 >> 9, l0 = mg0 & 511;
            if (matq == 0) {
#pragma unroll
                for (int r = 0; r < 4; ++r)
                    qo[(((size_t)bb * NH + h) * SEQ + (l0 + r)) * HD + d] =
                        f2bs((acc[ri][ci][r] + bvv) * qscale);
            } else if (matq == 1) {
#pragma unroll
                for (int r = 0; r < 4; ++r)
                    ko[(((size_t)bb * NH + h) * SEQ + (l0 + r)) * HD + d] =
                        f2bs(acc[ri][ci][r] + bvv);
            } else {
                unsigned u0 = (unsigned short)f2bs(acc[ri][ci][0] + bvv) |
                              ((unsigned)(unsigned short)f2bs(acc[ri][ci][1] + bvv) << 16);
                unsigned u1 = (unsigned short)f2bs(acc[ri][ci][2] + bvv) |
                              ((unsigned)(unsigned short)f2bs(acc[ri][ci][3] + bvv) << 16);
                uint2 pk; pk.x = u0; pk.y = u1;
                *(uint2*)&vto[(((size_t)bb * NH + h) * HD + d) * SEQ + l0] = pk;
            }
        }
    }
}

// ---------- barrier-free biaffine attention ----------
// block = (64 q-rows of one (b,h)); 256 threads / 4 waves; wave w owns rows w*16..+15.
// All K/V/bili operands read directly from global as MFMA fragments; LDS only for the
// per-wave P/Qp C->A transpose chunks. One __syncthreads total (abt table).
// Softmax: fixed-shift exp2 (shift-invariant), per-lane l partials, one epilogue reduce.
__global__ __launch_bounds__(256) void attn_mfma(
    const short* __restrict__ q, const short* __restrict__ k, const short* __restrict__ vt,
    const unsigned char* __restrict__ mp, const float* __restrict__ amask,
    const short* __restrict__ bilit, const float* __restrict__ abs_bias,
    float* __restrict__ out)
{
    __shared__ short Pw[4][16 * 72];  // per-wave transpose scratch
    __shared__ float abt[32];         // LOG2E*0.125*sum(bits*ab) - 23 (fixed exp2 shift)

    const int idx = blockIdx.x;            // it*192 + bh  (same bh spread across consecutive idx)
    const int bh = idx % 192, it = idx / 192;
    const int b = bh / NH, h = bh % NH;
    const int i0 = it * 64;
    const int tid = threadIdx.x, lane = tid & 63, w = tid >> 6;
    const int q4 = lane >> 4, c15 = lane & 15;

    const short* qg = q + (size_t)bh * SEQ * HD;
    const short* kg = k + (size_t)bh * SEQ * HD;
    const short* vg = vt + (size_t)bh * HD * SEQ;

    if (tid < 32) {
        float a = 0.f;
#pragma unroll
        for (int s = 0; s < NS; ++s)
            if (tid & (1u << s)) a += abs_bias[s * NH + h];
        abt[tid] = a * (0.125f * LOG2E) - 23.0f;
    }
    __syncthreads();

    // Q A-fragments straight from global
    short8 aQ0 = *(const short8*)&qg[(size_t)(i0 + w * 16 + c15) * HD + q4 * 8];
    short8 aQ1 = *(const short8*)&qg[(size_t)(i0 + w * 16 + c15) * HD + 32 + q4 * 8];

    // Qp_s = Q @ bili^T[s,h]; B-frags direct from global, C->A transpose via wave-private LDS
    short* pw = &Pw[w][0];
    short8 aP[NS][2];
#pragma unroll
    for (int s = 0; s < NS; ++s) {
        const short* bt = bilit + ((size_t)s * NH + h) * 4096;
#pragma unroll
        for (int ns = 0; ns < 4; ++ns) {
            short8 bf0 = *(const short8*)&bt[(ns * 16 + c15) * 64 + q4 * 8];
            short8 bf1 = *(const short8*)&bt[(ns * 16 + c15) * 64 + 32 + q4 * 8];
            floatx4 acc = {0.f, 0.f, 0.f, 0.f};
            acc = MFMA16(aQ0, bf0, acc);
            acc = MFMA16(aQ1, bf1, acc);
#pragma unroll
            for (int r = 0; r < 4; ++r)
                pw[(q4 * 4 + r) * 72 + ns * 16 + c15] = f2bs(acc[r]);
        }
        aP[s][0] = *(const short8*)&pw[c15 * 72 + q4 * 8];
        aP[s][1] = *(const short8*)&pw[c15 * 72 + 32 + q4 * 8];
    }

    float l_part[4] = {0.f, 0.f, 0.f, 0.f};
    floatx4 O[4];
#pragma unroll
    for (int d = 0; d < 4; ++d) O[d] = (floatx4){0.f, 0.f, 0.f, 0.f};

    const int ibase = i0 + w * 16 + q4 * 4;
    const unsigned char* mbp = mp + (size_t)b * SEQ * SEQ + (size_t)ibase * SEQ + c15;
    const float* amrow = amask + b * SEQ;

    for (int jt = 0; jt < 4; ++jt) {
        const int j0 = jt * 128;
#pragma unroll
        for (int js = 0; js < 8; ++js) {
            const int jr = j0 + js * 16;     // row block base in K
            short8 kf0 = *(const short8*)&kg[(size_t)(jr + c15) * HD + q4 * 8];
            short8 kf1 = *(const short8*)&kg[(size_t)(jr + c15) * HD + 32 + q4 * 8];

            floatx4 a0 = {0.f, 0.f, 0.f, 0.f};
            a0 = MFMA16(aQ0, kf0, a0);
            a0 = MFMA16(aQ1, kf1, a0);
            floatx4 as_[NS];
#pragma unroll
            for (int s = 0; s < NS; ++s) {
                floatx4 t = {0.f, 0.f, 0.f, 0.f};
                t = MFMA16(aP[s][0], kf0, t);
                t = MFMA16(aP[s][1], kf1, t);
                as_[s] = t;
            }
            const float am = amrow[jr + c15] * LOG2E;
#pragma unroll
            for (int r = 0; r < 4; ++r) {
                unsigned mb = mbp[r * SEQ + jr];
                float sc = a0[r] + am + abt[mb & 31];
#pragma unroll
                for (int s = 0; s < NS; ++s)
                    sc = fmaf((float)((mb >> s) & 1u), as_[s][r], sc);
                float p = __builtin_amdgcn_exp2f(sc);  // hardware v_exp_f32, log2-domain score
                l_part[r] += p;
                pw[(q4 * 4 + r) * 72 + (js & 1) * 16 + c15] = f2bs(p);
            }
            if (js & 1) {
                short8 pA = *(const short8*)&pw[c15 * 72 + q4 * 8];
                const int kk = js >> 1;
#pragma unroll
                for (int d = 0; d < 4; ++d) {
                    short8 vb = *(const short8*)&vg[(size_t)(d * 16 + c15) * SEQ + j0 + kk * 32 + q4 * 8];
                    O[d] = MFMA16(pA, vb, O[d]);
                }
            }
        }
    }

    // epilogue: reduce l across the 16 j-lanes, normalize, store
#pragma unroll
    for (int r = 0; r < 4; ++r) {
        float l = l_part[r];
        l += __shfl_xor(l, 1);
        l += __shfl_xor(l, 2);
        l += __shfl_xor(l, 4);
        l += __shfl_xor(l, 8);
        float inv = 1.f / l;
        float* orow = out + ((size_t)b * SEQ + ibase + r) * HID + h * HD;
#pragma unroll
        for (int d = 0; d < 4; ++d)
            orow[d * 16 + c15] = O[d][r] * inv;
    }
}

extern "C" void kernel_launch(void* const* d_in, const int* in_sizes, int n_in,
                              void* d_out, int out_size, void* d_ws, size_t ws_size,
                              hipStream_t stream) {
    const float* hidden   = (const float*)d_in[0];
    const float* amask    = (const float*)d_in[1];
    const float* smask    = (const float*)d_in[2];
    const float* Wq       = (const float*)d_in[3];
    const float* bq       = (const float*)d_in[4];
    const float* Wk       = (const float*)d_in[5];
    const float* bk       = (const float*)d_in[6];
    const float* Wv       = (const float*)d_in[7];
    const float* bv       = (const float*)d_in[8];
    const float* bili     = (const float*)d_in[9];
    const float* abs_bias = (const float*)d_in[10];
    float* out = (float*)d_out;

    char* ws = (char*)d_ws;
    const size_t QKV = (size_t)BATCH * NH * SEQ * HD * 2;
    short* qb   = (short*)(ws);
    short* kb   = (short*)(ws + QKV);
    short* vtb  = (short*)(ws + 2 * QKV);
    short* xb   = (short*)(ws + 3 * QKV);
    short* Wb   = (short*)(ws + 4 * QKV);
    short* bltb = (short*)(ws + 4 * QKV + (size_t)3 * HID * HID * 2);
    unsigned char* mpk = (unsigned char*)(ws + 4 * QKV + (size_t)3 * HID * HID * 2
                                          + (size_t)NS * NH * HD * HD * 2);

    prep_kernel<<<8092, 256, 0, stream>>>(hidden, Wq, Wk, Wv, bili, smask,
                                          xb, Wb, bltb, (uchar4*)mpk);

    proj_mfma<<<dim3(BATCH * SEQ / 128, 3 * HID / 128), 256, 0, stream>>>(
        xb, Wb, bq, bk, bv, qb, kb, vtb);

    attn_mfma<<<(SEQ / 64) * NH * BATCH, 256, 0, stream>>>(
        qb, kb, vtb, mpk, amask, bltb, abs_bias, out);
}

// Round 8
// 333.237 us; speedup vs baseline: 1.2331x; 1.2331x over previous
//
#include <hip/hip_runtime.h>
#include <hip/hip_bf16.h>

#define BATCH 16
#define SEQ   512
#define HID   768
#define NH    12
#define HD    64
#define NS    5
#define LOG2E 1.44269504f

typedef __attribute__((ext_vector_type(8))) short short8;
typedef __attribute__((ext_vector_type(4))) short bs4;
typedef __attribute__((ext_vector_type(4))) float floatx4;

#define MFMA16(a, b, c) __builtin_amdgcn_mfma_f32_16x16x32_bf16((a), (b), (c), 0, 0, 0)

// async global->LDS, 16B per lane, dest = ldsbase + lane*16
#define GLOAD16(gp, lp) __builtin_amdgcn_global_load_lds( \
    (const __attribute__((address_space(1))) unsigned*)(gp), \
    (__attribute__((address_space(3))) unsigned*)(lp), 16, 0, 0)

static __device__ __forceinline__ short f2bs(float f) {
    // fp32 -> bf16 RNE (finite inputs)
    unsigned x = __builtin_bit_cast(unsigned, f);
    return (short)((x + 0x7fffu + ((x >> 16) & 1u)) >> 16);
}

// ---------- fused prep: hidden cvt | W cvt | bili transpose | mask pack ----------
__global__ __launch_bounds__(256) void prep_kernel(
    const float* __restrict__ hidden, const float* __restrict__ wq,
    const float* __restrict__ wk, const float* __restrict__ wv,
    const float* __restrict__ bili, const float* __restrict__ smask,
    short* __restrict__ xb, short* __restrict__ Wb, short* __restrict__ bltb,
    uchar4* __restrict__ mpk)
{
    __shared__ short Tl[64][72];
    const int bid = blockIdx.x, tid = threadIdx.x;

    if (bid < 3072) {                       // hidden: 786432 groups of 8
        int i = bid * 256 + tid;
        float4 a = ((const float4*)hidden)[2 * i];
        float4 b = ((const float4*)hidden)[2 * i + 1];
        short8 o;
        o[0] = f2bs(a.x); o[1] = f2bs(a.y); o[2] = f2bs(a.z); o[3] = f2bs(a.w);
        o[4] = f2bs(b.x); o[5] = f2bs(b.y); o[6] = f2bs(b.z); o[7] = f2bs(b.w);
        ((short8*)xb)[i] = o;
    } else if (bid < 3936) {                // W: 3 mats x 288 blocks
        int seg = bid - 3072;
        int mat = seg / 288, blk = seg % 288;
        const float* src = (mat == 0) ? wq : (mat == 1) ? wk : wv;
        int i = blk * 256 + tid;
        float4 a = ((const float4*)src)[2 * i];
        float4 b = ((const float4*)src)[2 * i + 1];
        short8 o;
        o[0] = f2bs(a.x); o[1] = f2bs(a.y); o[2] = f2bs(a.z); o[3] = f2bs(a.w);
        o[4] = f2bs(b.x); o[5] = f2bs(b.y); o[6] = f2bs(b.z); o[7] = f2bs(b.w);
        ((short8*)(Wb + (size_t)mat * HID * HID))[i] = o;
    } else if (bid < 3996) {                // bilit: [s,h,p,q] -> bf16 [s,h,q,p]
        int sh = bid - 3936;
        const float* src = bili + (size_t)sh * 4096;
        short* dst = bltb + (size_t)sh * 4096;
        for (int t = tid; t < 4096; t += 256) Tl[t >> 6][t & 63] = f2bs(src[t]);
        __syncthreads();
        for (int t = tid; t < 4096; t += 256) dst[t] = Tl[t & 63][t >> 6];
    } else {                                // pack 5 masks into bitfield bytes
        int i = (bid - 3996) * 256 + tid;   // over B*L*L/4
        const size_t BLL4 = (size_t)BATCH * SEQ * SEQ / 4;
        const float4* f = (const float4*)smask;
        unsigned b0 = 0, b1 = 0, b2 = 0, b3 = 0;
#pragma unroll
        for (int s = 0; s < NS; ++s) {
            float4 v = f[(size_t)s * BLL4 + i];
            b0 |= (v.x != 0.f) ? (1u << s) : 0u;
            b1 |= (v.y != 0.f) ? (1u << s) : 0u;
            b2 |= (v.z != 0.f) ? (1u << s) : 0u;
            b3 |= (v.w != 0.f) ? (1u << s) : 0u;
        }
        mpk[i] = make_uchar4((unsigned char)b0, (unsigned char)b1, (unsigned char)b2, (unsigned char)b3);
    }
}

// ---------- QKV projection: 128x128 tile + global_load_lds + LDS-transpose epilogue ----------
// q pre-scaled by 0.125*LOG2E; k raw; v -> transposed [B,H,D,L].
// 32 KB shared pool: staging (As/Bs, 16 KB) then per-wave 8 KB epilogue scratch (4x8=32 KB).
__global__ __launch_bounds__(256) void proj_mfma(
    const short* __restrict__ xb, const short* __restrict__ Wb,
    const float* __restrict__ bq, const float* __restrict__ bk, const float* __restrict__ bv,
    short* __restrict__ qo, short* __restrict__ ko, short* __restrict__ vto)
{
    __shared__ short SMEM[16384];    // 32 KB pool
    short* As = SMEM;                // 128*32 shorts (8 KB)
    short* Bs = SMEM + 4096;         // 128*32 shorts (8 KB)

    const int tid = threadIdx.x, lane = tid & 63, w = tid >> 6;
    const int q4 = lane >> 4, c15 = lane & 15;
    const int m0 = blockIdx.x * 128, n0 = blockIdx.y * 128;
    const int wrow = (w & 1) * 64, wcol = (w >> 1) * 64;

    const int srow = lane >> 2;
    const int scol = (lane & 3) * 8;
    const short* gA = xb + (size_t)(m0 + w * 32 + srow) * HID + scol;
    const short* gB = Wb + (size_t)(n0 + w * 32 + srow) * HID + scol;
    short* lA = As + w * 1024;
    short* lB = Bs + w * 1024;

    floatx4 acc[4][4];
#pragma unroll
    for (int i = 0; i < 4; ++i)
#pragma unroll
        for (int j = 0; j < 4; ++j) acc[i][j] = (floatx4){0.f, 0.f, 0.f, 0.f};

    for (int k0 = 0; k0 < HID; k0 += 32) {
        __syncthreads();
        GLOAD16(gA + k0,            lA);
        GLOAD16(gA + k0 + 16 * HID, lA + 512);
        GLOAD16(gB + k0,            lB);
        GLOAD16(gB + k0 + 16 * HID, lB + 512);
        __syncthreads();

        short8 af[4], bf[4];
#pragma unroll
        for (int ri = 0; ri < 4; ++ri)
            af[ri] = *(const short8*)&As[(wrow + ri * 16 + c15) * 32 + q4 * 8];
#pragma unroll
        for (int ci = 0; ci < 4; ++ci)
            bf[ci] = *(const short8*)&Bs[(wcol + ci * 16 + c15) * 32 + q4 * 8];
#pragma unroll
        for (int ri = 0; ri < 4; ++ri)
#pragma unroll
            for (int ci = 0; ci < 4; ++ci)
                acc[ri][ci] = MFMA16(af[ri], bf[ci], acc[ri][ci]);
    }

    __syncthreads();   // all frag reads done before reusing pool as epilogue scratch

    // per-wave disjoint 8 KB scratch (4096 shorts = 64x64 bf16 chunk)
    short* Sw = SMEM + w * 4096;

    const int matq = n0 / HID;                         // 0,1,2 (block-uniform)
    const float* bias = (matq == 0) ? bq : (matq == 1) ? bk : bv;
    const int nmBase = (n0 - matq * HID) + wcol;       // multiple of 64
    const int h = nmBase >> 6;                         // head (wave-uniform)
    const int mg0 = m0 + wrow;                         // 64-aligned
    const int bb = mg0 >> 9, l0 = mg0 & 511;

    if (matq < 2) {
        const float qsc = (matq == 0) ? (0.125f * LOG2E) : 1.0f;
        // Sw[row=L][col=d], 16B-chunk swizzle: physchunk = (col>>3) ^ (row&7)
#pragma unroll
        for (int ci = 0; ci < 4; ++ci) {
            const int col = ci * 16 + c15;
            const float bv2 = bias[nmBase + col];
#pragma unroll
            for (int ri = 0; ri < 4; ++ri)
#pragma unroll
                for (int r = 0; r < 4; ++r) {
                    const int row = ri * 16 + q4 * 4 + r;
                    const int phys = (row << 6) + ((((col >> 3) ^ (row & 7)) << 3) | (col & 7));
                    Sw[phys] = f2bs((acc[ri][ci][r] + bv2) * qsc);
                }
        }
        short* dst = (matq == 0) ? qo : ko;
#pragma unroll
        for (int it2 = 0; it2 < 8; ++it2) {
            const int row = it2 * 8 + (lane >> 3);
            const int g = lane & 7;
            short8 val = *(const short8*)&Sw[(row << 6) + ((g ^ (row & 7)) << 3)];
            *(short8*)&dst[(((size_t)bb * NH + h) * SEQ + (l0 + row)) * HD + g * 8] = val;
        }
    } else {
        // Sw[d][l] (transposed chunk), same swizzle on l-chunks
#pragma unroll
        for (int ci = 0; ci < 4; ++ci) {
            const int d = ci * 16 + c15;
            const float bv2 = bias[nmBase + d];
#pragma unroll
            for (int ri = 0; ri < 4; ++ri) {
                bs4 v4;
#pragma unroll
                for (int r = 0; r < 4; ++r) v4[r] = f2bs(acc[ri][ci][r] + bv2);
                const int lbase = ri * 16 + q4 * 4;
                const int phys = (d << 6) + ((((lbase >> 3) ^ (d & 7)) << 3) | (lbase & 7));
                *(bs4*)&Sw[phys] = v4;
            }
        }
#pragma unroll
        for (int it2 = 0; it2 < 8; ++it2) {
            const int d = it2 * 8 + (lane >> 3);
            const int g = lane & 7;
            short8 val = *(const short8*)&Sw[(d << 6) + ((g ^ (d & 7)) << 3)];
            *(short8*)&vto[(((size_t)bb * NH + h) * HD + d) * SEQ + l0 + g * 8] = val;
        }
    }
}

// ---------- fused biaffine attention: LDS-staged K/V + exp2 fixed-shift softmax ----------
// block = (64 q-rows of one (b,h)); 256 threads / 4 waves; wave w owns rows w*16..+15.
__global__ __launch_bounds__(256) void attn_mfma(
    const short* __restrict__ q, const short* __restrict__ k, const short* __restrict__ vt,
    const unsigned char* __restrict__ mp, const float* __restrict__ amask,
    const short* __restrict__ bilit, const float* __restrict__ abs_bias,
    float* __restrict__ out)
{
    __shared__ short Ks[64 * 72];     // K rows (stride 72)
    __shared__ short Vs[64 * 72];     // V^T rows [d][j]
    __shared__ short Pw[4][16 * 72];  // per-wave P/Qp transpose scratch
    __shared__ float abt[32];         // LOG2E*0.125*sum(bits*ab) - 23 (fixed exp2 shift)

    const int idx = blockIdx.x;
    const int bh = idx % 192, it = idx / 192;
    const int b = bh / NH, h = bh % NH;
    const int i0 = it * 64;
    const int tid = threadIdx.x, lane = tid & 63, w = tid >> 6;
    const int q4 = lane >> 4, c15 = lane & 15;

    const short* qg = q + (size_t)bh * SEQ * HD;
    const short* kg = k + (size_t)bh * SEQ * HD;
    const short* vg = vt + (size_t)bh * HD * SEQ;

    if (tid < 32) {
        float a = 0.f;
#pragma unroll
        for (int s = 0; s < NS; ++s)
            if (tid & (1u << s)) a += abs_bias[s * NH + h];
        abt[tid] = a * (0.125f * LOG2E) - 23.0f;
    }
    __syncthreads();

    // Q A-fragments straight from global (read once)
    short8 aQ0 = *(const short8*)&qg[(size_t)(i0 + w * 16 + c15) * HD + q4 * 8];
    short8 aQ1 = *(const short8*)&qg[(size_t)(i0 + w * 16 + c15) * HD + 32 + q4 * 8];

    // Qp_s = Q @ bili^T[s,h]; B-frags direct from global (tiny, L2-hot),
    // C->A transpose via wave-private LDS chunk (no barrier needed)
    short* pw = &Pw[w][0];
    short8 aP[NS][2];
#pragma unroll
    for (int s = 0; s < NS; ++s) {
        const short* bt = bilit + ((size_t)s * NH + h) * 4096;
#pragma unroll
        for (int ns = 0; ns < 4; ++ns) {
            short8 bf0 = *(const short8*)&bt[(ns * 16 + c15) * 64 + q4 * 8];
            short8 bf1 = *(const short8*)&bt[(ns * 16 + c15) * 64 + 32 + q4 * 8];
            floatx4 acc = {0.f, 0.f, 0.f, 0.f};
            acc = MFMA16(aQ0, bf0, acc);
            acc = MFMA16(aQ1, bf1, acc);
#pragma unroll
            for (int r = 0; r < 4; ++r)
                pw[(q4 * 4 + r) * 72 + ns * 16 + c15] = f2bs(acc[r]);
        }
        aP[s][0] = *(const short8*)&pw[c15 * 72 + q4 * 8];
        aP[s][1] = *(const short8*)&pw[c15 * 72 + 32 + q4 * 8];
    }

    float l_part[4] = {0.f, 0.f, 0.f, 0.f};
    floatx4 O[4];
#pragma unroll
    for (int d = 0; d < 4; ++d) O[d] = (floatx4){0.f, 0.f, 0.f, 0.f};

    const int ibase = i0 + w * 16 + q4 * 4;
    const unsigned char* mbp = mp + (size_t)b * SEQ * SEQ + (size_t)ibase * SEQ + c15;
    const float* amrow = amask + b * SEQ;

    for (int jt = 0; jt < 8; ++jt) {
        const int j0 = jt * 64;
        __syncthreads();  // prior-iter K/V readers done
        for (int c = tid; c < 512; c += 256) {
            int r = c >> 3, o = (c & 7) * 8;
            *(short8*)&Ks[r * 72 + o] = *(const short8*)&kg[(size_t)(j0 + r) * HD + o];
            *(short8*)&Vs[r * 72 + o] = *(const short8*)&vg[(size_t)r * SEQ + j0 + o];
        }
        __syncthreads();

#pragma unroll
        for (int js = 0; js < 4; ++js) {
            const int jr = j0 + js * 16;
            short8 kf0 = *(const short8*)&Ks[(js * 16 + c15) * 72 + q4 * 8];
            short8 kf1 = *(const short8*)&Ks[(js * 16 + c15) * 72 + 32 + q4 * 8];

            floatx4 a0 = {0.f, 0.f, 0.f, 0.f};
            a0 = MFMA16(aQ0, kf0, a0);
            a0 = MFMA16(aQ1, kf1, a0);
            floatx4 as_[NS];
#pragma unroll
            for (int s = 0; s < NS; ++s) {
                floatx4 t = {0.f, 0.f, 0.f, 0.f};
                t = MFMA16(aP[s][0], kf0, t);
                t = MFMA16(aP[s][1], kf1, t);
                as_[s] = t;
            }
            const float am = amrow[jr + c15] * LOG2E;
#pragma unroll
            for (int r = 0; r < 4; ++r) {
                unsigned mb = mbp[r * SEQ + jr];
                float sc = a0[r] + am + abt[mb & 31];
#pragma unroll
                for (int s = 0; s < NS; ++s)
                    sc = fmaf((float)((mb >> s) & 1u), as_[s][r], sc);
                float p = __builtin_amdgcn_exp2f(sc);
                l_part[r] += p;
                pw[(q4 * 4 + r) * 72 + (js & 1) * 16 + c15] = f2bs(p);
            }
            if (js & 1) {
                short8 pA = *(const short8*)&pw[c15 * 72 + q4 * 8];
                const int kk = js >> 1;
#pragma unroll
                for (int d = 0; d < 4; ++d) {
                    short8 vb = *(const short8*)&Vs[(d * 16 + c15) * 72 + kk * 32 + q4 * 8];
                    O[d] = MFMA16(pA, vb, O[d]);
                }
            }
        }
    }

    // epilogue: reduce l across the 16 j-lanes, normalize, store
#pragma unroll
    for (int r = 0; r < 4; ++r) {
        float l = l_part[r];
        l += __shfl_xor(l, 1);
        l += __shfl_xor(l, 2);
        l += __shfl_xor(l, 4);
        l += __shfl_xor(l, 8);
        float inv = 1.f / l;
        float* orow = out + ((size_t)b * SEQ + ibase + r) * HID + h * HD;
#pragma unroll
        for (int d = 0; d < 4; ++d)
            orow[d * 16 + c15] = O[d][r] * inv;
    }
}

extern "C" void kernel_launch(void* const* d_in, const int* in_sizes, int n_in,
                              void* d_out, int out_size, void* d_ws, size_t ws_size,
                              hipStream_t stream) {
    const float* hidden   = (const float*)d_in[0];
    const float* amask    = (const float*)d_in[1];
    const float* smask    = (const float*)d_in[2];
    const float* Wq       = (const float*)d_in[3];
    const float* bq       = (const float*)d_in[4];
    const float* Wk       = (const float*)d_in[5];
    const float* bk       = (const float*)d_in[6];
    const float* Wv       = (const float*)d_in[7];
    const float* bv       = (const float*)d_in[8];
    const float* bili     = (const float*)d_in[9];
    const float* abs_bias = (const float*)d_in[10];
    float* out = (float*)d_out;

    char* ws = (char*)d_ws;
    const size_t QKV = (size_t)BATCH * NH * SEQ * HD * 2;
    short* qb   = (short*)(ws);
    short* kb   = (short*)(ws + QKV);
    short* vtb  = (short*)(ws + 2 * QKV);
    short* xb   = (short*)(ws + 3 * QKV);
    short* Wb   = (short*)(ws + 4 * QKV);
    short* bltb = (short*)(ws + 4 * QKV + (size_t)3 * HID * HID * 2);
    unsigned char* mpk = (unsigned char*)(ws + 4 * QKV + (size_t)3 * HID * HID * 2
                                          + (size_t)NS * NH * HD * HD * 2);

    prep_kernel<<<8092, 256, 0, stream>>>(hidden, Wq, Wk, Wv, bili, smask,
                                          xb, Wb, bltb, (uchar4*)mpk);

    proj_mfma<<<dim3(BATCH * SEQ / 128, 3 * HID / 128), 256, 0, stream>>>(
        xb, Wb, bq, bk, bv, qb, kb, vtb);

    attn_mfma<<<(SEQ / 64) * NH * BATCH, 256, 0, stream>>>(
        qb, kb, vtb, mpk, amask, bltb, abs_bias, out);
}